// Round 3
// baseline (421.621 us; speedup 1.0000x reference)
//
#include <hip/hip_runtime.h>
#include <hip/hip_bf16.h>

// Problem: B=2,S=2048 -> T=4096 tokens; D=1024; N=64 experts; R=64; TOP_K=2.
// Inputs runtime-detected f32 vs bf16 (measured: f32). Output buffer is FLOAT32
// (round-2 evidence: bf16 writes read back as f32 gave absmax 64.625 = idx 63
// bleeding into proj region at the halfway point).
// d_out layout (f32): [0,262144) proj; [262144,270336) topk_idx (as float);
// [270336,278528) topk_w.
// d_ws: [0,2MB) f32 proj[t][slot][r]; + int idx[t*2]; + f32 w[t*2]; + int flag.

typedef unsigned short u16;

__device__ __forceinline__ float bf2f(u16 u) {
    unsigned int v = ((unsigned int)u) << 16;
    float f;
    __builtin_memcpy(&f, &v, 4);
    return f;
}

#define T_TOKENS 4096
#define DDIM 1024
#define NEXP 64
#define RDIM 64
#define OUT_IDX_OFF 262144
#define OUT_W_OFF 270336

struct LdBF {
    const u16* p;
    __device__ __forceinline__ float4 ld4(size_t i) const {
        ushort4 v = *(const ushort4*)(p + i);
        return make_float4(bf2f(v.x), bf2f(v.y), bf2f(v.z), bf2f(v.w));
    }
};
struct LdF32 {
    const float* p;
    __device__ __forceinline__ float4 ld4(size_t i) const { return *(const float4*)(p + i); }
};

// ---------------- dtype detect: 0 = bf16, 1 = f32 ----------------
__global__ __launch_bounds__(512) void detect_dtype(const u16* __restrict__ x, int* __restrict__ flag) {
    __shared__ int cnt;
    if (threadIdx.x == 0) cnt = 0;
    __syncthreads();
    unsigned e = (x[threadIdx.x] >> 7) & 0xFF;
    atomicAdd(&cnt, (e >= 0x68 && e <= 0x88) ? 1 : 0);
    __syncthreads();
    if (threadIdx.x == 0) *flag = (cnt >= 480) ? 0 : 1;
}

// ---------------- Kernel A: router scores + top2 + softmax ----------------
// 512 blocks x 256 threads, 8 tokens/block.
template <class LD>
__device__ __forceinline__ void score_body(LD xld, LD rwld, float* xsf, float* sc,
                                           float* out, int* wsI, float* wsW) {
    const int tid = threadIdx.x;
    const size_t t0 = (size_t)blockIdx.x * 8;

    for (int i = tid * 4; i < 8 * DDIM; i += 1024)
        *(float4*)&xsf[i] = xld.ld4(t0 * DDIM + i);
    __syncthreads();

    const int n = tid & 63;
    const int q = tid >> 6;  // tokens 2q, 2q+1
    float a0 = 0.f, a1 = 0.f;
    for (int d = 0; d < DDIM; d += 4) {
        float4 rv = rwld.ld4((size_t)n * DDIM + d);
        float4 x0 = *(const float4*)&xsf[(2 * q) * DDIM + d];
        float4 x1 = *(const float4*)&xsf[(2 * q + 1) * DDIM + d];
        a0 += x0.x * rv.x + x0.y * rv.y + x0.z * rv.z + x0.w * rv.w;
        a1 += x1.x * rv.x + x1.y * rv.y + x1.z * rv.z + x1.w * rv.w;
    }
    sc[(2 * q) * NEXP + n] = a0;
    sc[(2 * q + 1) * NEXP + n] = a1;
    __syncthreads();

    if (tid < 8) {
        const float* s = &sc[tid * NEXP];
        float best = -1e30f, secv = -1e30f;
        int bi = 0, si = 0;
        for (int j = 0; j < NEXP; ++j) {
            float v = s[j];
            if (v > best) { secv = best; si = bi; best = v; bi = j; }
            else if (v > secv) { secv = v; si = j; }
        }
        float w0 = 1.0f / (1.0f + expf(secv - best));
        float w1 = 1.0f - w0;
        size_t t = t0 + tid;
        out[OUT_IDX_OFF + t * 2 + 0] = (float)bi;
        out[OUT_IDX_OFF + t * 2 + 1] = (float)si;
        out[OUT_W_OFF + t * 2 + 0] = w0;
        out[OUT_W_OFF + t * 2 + 1] = w1;
        wsI[t * 2 + 0] = bi; wsI[t * 2 + 1] = si;
        wsW[t * 2 + 0] = w0; wsW[t * 2 + 1] = w1;
    }
}

__global__ __launch_bounds__(256) void score_topk(const void* x, const void* rw,
                                                  float* out, int* wsI, float* wsW,
                                                  const int* flag) {
    __shared__ float xsf[8 * DDIM];
    __shared__ float sc[8 * NEXP];
    if (*flag)
        score_body(LdF32{(const float*)x}, LdF32{(const float*)rw}, xsf, sc, out, wsI, wsW);
    else
        score_body(LdBF{(const u16*)x}, LdBF{(const u16*)rw}, xsf, sc, out, wsI, wsW);
}

// ---------------- Kernel B: expert projections ----------------
// 512 blocks: expert n = b & 63 (XCD-swizzled), token chunk c = b >> 6. 256 thr.
template <class LD>
__device__ __forceinline__ void proj_body(LD xld, LD nld, const int* wsI, float* wsProj,
                                          float* xs, float* part) {
    const int tid = threadIdx.x;
    const int n = blockIdx.x & 63;
    const int c = blockIdx.x >> 6;
    const int tbeg = c * 512, tend = tbeg + 512;
    const int rp = tid & 15;  // r = 4*rp..4*rp+3
    const int j = tid >> 4;   // d = 64*j..64*j+63
    const size_t noff = ((size_t)n << 16) + (size_t)(j * 64) * RDIM + rp * 4;

    for (int t = tbeg; t < tend; ++t) {
        const int i0 = wsI[t * 2], i1 = wsI[t * 2 + 1];
        const int s = (i0 == n) ? 0 : ((i1 == n) ? 1 : -1);
        if (s < 0) continue;  // block-uniform

        *(float4*)&xs[tid * 4] = xld.ld4((size_t)t * DDIM + tid * 4);
        __syncthreads();

        float a0 = 0.f, a1 = 0.f, a2 = 0.f, a3 = 0.f;
        const float* xp = &xs[j * 64];
#pragma unroll 8
        for (int dd = 0; dd < 64; ++dd) {
            const float xv = xp[dd];
            float4 nv = nld.ld4(noff + (size_t)dd * RDIM);
            a0 += xv * nv.x; a1 += xv * nv.y; a2 += xv * nv.z; a3 += xv * nv.w;
        }
        float* pp = &part[j * 64 + rp * 4];
        pp[0] = a0; pp[1] = a1; pp[2] = a2; pp[3] = a3;
        __syncthreads();

        if (tid < 64) {
            float sum = 0.f;
#pragma unroll
            for (int jj = 0; jj < 16; ++jj) sum += part[jj * 64 + tid];
            wsProj[((size_t)t * 2 + s) * RDIM + tid] = sum;
        }
        __syncthreads();
    }
}

__global__ __launch_bounds__(256) void expert_proj(const void* x, const void* neurons,
                                                   const int* wsI, float* wsProj,
                                                   const int* flag) {
    __shared__ float xs[DDIM];
    __shared__ float part[16 * 64];
    if (*flag)
        proj_body(LdF32{(const float*)x}, LdF32{(const float*)neurons}, wsI, wsProj, xs, part);
    else
        proj_body(LdBF{(const u16*)x}, LdBF{(const u16*)neurons}, wsI, wsProj, xs, part);
}

// ---------------- Kernel C: combine w0*p0 + w1*p1 -> f32 ----------------
__global__ __launch_bounds__(256) void combine(const float* __restrict__ wsProj,
                                               const float* __restrict__ wsW,
                                               float* __restrict__ out) {
    const int g = blockIdx.x * 256 + threadIdx.x;  // 0..262143
    const int t = g >> 6, r = g & 63;
    const float w0 = wsW[t * 2], w1 = wsW[t * 2 + 1];
    out[g] = w0 * wsProj[(size_t)t * 128 + r] + w1 * wsProj[(size_t)t * 128 + 64 + r];
}

extern "C" void kernel_launch(void* const* d_in, const int* in_sizes, int n_in,
                              void* d_out, int out_size, void* d_ws, size_t ws_size,
                              hipStream_t stream) {
    const void* x = d_in[0];
    const void* rw = d_in[1];
    const void* neurons = d_in[2];
    float* out = (float*)d_out;

    float* wsProj = (float*)d_ws;  // 4096*2*64 f32 = 2 MB
    int* wsI = (int*)((char*)d_ws + (size_t)T_TOKENS * 2 * RDIM * 4);
    float* wsW = (float*)((char*)wsI + (size_t)T_TOKENS * 2 * 4);
    int* wsFlag = (int*)((char*)wsW + (size_t)T_TOKENS * 2 * 4);

    detect_dtype<<<1, 512, 0, stream>>>((const u16*)x, wsFlag);
    score_topk<<<512, 256, 0, stream>>>(x, rw, out, wsI, wsW, wsFlag);
    expert_proj<<<512, 256, 0, stream>>>(x, neurons, wsI, wsProj, wsFlag);
    combine<<<1024, 256, 0, stream>>>(wsProj, wsW, out);
}

// Round 4
// 209.537 us; speedup vs baseline: 2.0122x; 2.0122x over previous
//
#include <hip/hip_runtime.h>
#include <hip/hip_bf16.h>

// B=2,S=2048 -> T=4096 tokens; D=1024; N=64 experts; R=64; TOP_K=2.
// Inputs runtime-detected f32 vs bf16 (measured: f32). Outputs f32 flat:
// [0,262144) proj; [262144,270336) topk_idx (as float); [270336,278528) topk_w.
// Round-4 restructure: counting-sort tokens per expert, then dense tiled GEMM
// per expert (round-3 expert_proj was latency-bound: VALUBusy 4%, occ 13%).
// d_ws: [0,2MB) f32 proj[t*2+s][r]; +2MB f32 w[t*2] (32KB); + int cnt[64];
//        + int list[64*1024] (256KB); + int flag.

typedef unsigned short u16;

__device__ __forceinline__ float bf2f(u16 u) {
    unsigned int v = ((unsigned int)u) << 16;
    float f;
    __builtin_memcpy(&f, &v, 4);
    return f;
}

#define T_TOKENS 4096
#define DDIM 1024
#define NEXP 64
#define RDIM 64
#define LCAP 1024
#define OUT_IDX_OFF 262144
#define OUT_W_OFF 270336

struct LdBF {
    const u16* p;
    __device__ __forceinline__ float4 ld4(size_t i) const {
        ushort4 v = *(const ushort4*)(p + i);
        return make_float4(bf2f(v.x), bf2f(v.y), bf2f(v.z), bf2f(v.w));
    }
};
struct LdF32 {
    const float* p;
    __device__ __forceinline__ float4 ld4(size_t i) const { return *(const float4*)(p + i); }
};

// ---------------- dtype detect: 0 = bf16, 1 = f32 ----------------
__global__ __launch_bounds__(512) void detect_dtype(const u16* __restrict__ x, int* __restrict__ flag) {
    __shared__ int cnt;
    if (threadIdx.x == 0) cnt = 0;
    __syncthreads();
    unsigned e = (x[threadIdx.x] >> 7) & 0xFF;
    atomicAdd(&cnt, (e >= 0x68 && e <= 0x88) ? 1 : 0);
    __syncthreads();
    if (threadIdx.x == 0) *flag = (cnt >= 480) ? 0 : 1;
}

// ---------------- Kernel A: score GEMM + top2 + softmax + expert lists ----
// 128 blocks x 256 threads; 32 tokens/block; K-chunks of 64.
// Per-(t,n) accumulation order == round 3 (d step 4, left-to-right float4
// expression) so top-2 tie decisions reproduce exactly.
template <class LD>
__device__ __forceinline__ void score_body(LD xld, LD rwld,
                                           float* xs /*32*64*/, float* wt /*64*68*/,
                                           float* sc /*32*65*/,
                                           float* out, float* wsW,
                                           int* wsCnt, int* wsList) {
    const int tid = threadIdx.x;
    const size_t t0 = (size_t)blockIdx.x * 32;
    const int mg = tid >> 4;   // 0..15 -> tokens 2mg, 2mg+1
    const int ng = tid & 15;   // experts 4ng..4ng+3

    float4 acc0[4], acc1[4];
#pragma unroll
    for (int k = 0; k < 4; ++k) { acc0[k] = make_float4(0,0,0,0); acc1[k] = make_float4(0,0,0,0); }
    float a0[4] = {0,0,0,0}, a1[4] = {0,0,0,0};

    for (int kc = 0; kc < 16; ++kc) {
        // stage x: 32 tokens x 64 d
#pragma unroll
        for (int h = 0; h < 2; ++h) {
            int i4 = tid + h * 256;
            int m = i4 >> 4, dd4 = (i4 & 15) * 4;
            *(float4*)&xs[m * 64 + dd4] = xld.ld4((t0 + m) * DDIM + kc * 64 + dd4);
        }
        // stage rw chunk: 64 n x 64 d, padded row 68
#pragma unroll
        for (int h = 0; h < 4; ++h) {
            int i4 = tid + h * 256;
            int n = i4 >> 4, dd4 = (i4 & 15) * 4;
            *(float4*)&wt[n * 68 + dd4] = rwld.ld4((size_t)n * DDIM + kc * 64 + dd4);
        }
        __syncthreads();

#pragma unroll 4
        for (int dd = 0; dd < 64; dd += 4) {
            float4 xa = *(const float4*)&xs[(2 * mg) * 64 + dd];
            float4 xb = *(const float4*)&xs[(2 * mg + 1) * 64 + dd];
#pragma unroll
            for (int k = 0; k < 4; ++k) {
                float4 wv = *(const float4*)&wt[(4 * ng + k) * 68 + dd];
                a0[k] += xa.x * wv.x + xa.y * wv.y + xa.z * wv.z + xa.w * wv.w;
                a1[k] += xb.x * wv.x + xb.y * wv.y + xb.z * wv.z + xb.w * wv.w;
            }
        }
        __syncthreads();
    }
    (void)acc0; (void)acc1;

    // scatter C tile to sc[32][65] (scalar stores; pad kills scan conflicts)
#pragma unroll
    for (int k = 0; k < 4; ++k) {
        sc[(2 * mg) * 65 + 4 * ng + k] = a0[k];
        sc[(2 * mg + 1) * 65 + 4 * ng + k] = a1[k];
    }
    __syncthreads();

    if (tid < 32) {
        const float* s = &sc[tid * 65];
        float best = -1e30f, secv = -1e30f;
        int bi = 0, si = 0;
        for (int j = 0; j < NEXP; ++j) {
            float v = s[j];
            if (v > best) { secv = best; si = bi; best = v; bi = j; }
            else if (v > secv) { secv = v; si = j; }
        }
        float w0 = 1.0f / (1.0f + expf(secv - best));
        float w1 = 1.0f - w0;
        size_t t = t0 + tid;
        out[OUT_IDX_OFF + t * 2 + 0] = (float)bi;
        out[OUT_IDX_OFF + t * 2 + 1] = (float)si;
        out[OUT_W_OFF + t * 2 + 0] = w0;
        out[OUT_W_OFF + t * 2 + 1] = w1;
        wsW[t * 2 + 0] = w0;
        wsW[t * 2 + 1] = w1;
        int p0 = atomicAdd(&wsCnt[bi], 1);
        if (p0 < LCAP) wsList[bi * LCAP + p0] = (int)(t * 2 + 0);
        int p1 = atomicAdd(&wsCnt[si], 1);
        if (p1 < LCAP) wsList[si * LCAP + p1] = (int)(t * 2 + 1);
    }
}

__global__ __launch_bounds__(256) void score_topk(const void* x, const void* rw,
                                                  float* out, float* wsW,
                                                  int* wsCnt, int* wsList,
                                                  const int* flag) {
    __shared__ float xs[32 * 64];
    __shared__ float wt[64 * 68];
    __shared__ float sc[32 * 65];
    if (*flag)
        score_body(LdF32{(const float*)x}, LdF32{(const float*)rw}, xs, wt, sc, out, wsW, wsCnt, wsList);
    else
        score_body(LdBF{(const u16*)x}, LdBF{(const u16*)rw}, xs, wt, sc, out, wsW, wsCnt, wsList);
}

// ---------------- Kernel B: per-expert tiled GEMM ----------------
// 512 blocks: expert n = bid & 63 (same-XCD tiles share L2), j = bid>>6 (0..7).
// M-tile 32 gathered tokens, K-chunks of 64, C = 32x64 in registers.
template <class LD>
__device__ __forceinline__ void egemm_body(LD xld, LD nld,
                                           const int* wsCnt, const int* wsList,
                                           float* wsProj,
                                           float* xs /*32*64*/, float* wt /*64*64*/,
                                           int* ent /*32*/) {
    const int tid = threadIdx.x;
    const int n = blockIdx.x & 63;
    const int j = blockIdx.x >> 6;
    const int cnt = min(wsCnt[n], LCAP);
    const int mg = tid >> 4;   // 0..15 -> rows 2mg, 2mg+1
    const int rg = tid & 15;   // r = 4rg..4rg+3
    const size_t nbase = (size_t)n * DDIM * RDIM;

    for (int base = j * 32; base < cnt; base += 256) {
        const int valid = min(32, cnt - base);
        if (tid < 32)
            ent[tid] = (tid < valid) ? wsList[n * LCAP + base + tid] : 0;
        __syncthreads();

        float4 acc0 = make_float4(0, 0, 0, 0), acc1 = make_float4(0, 0, 0, 0);
        for (int kc = 0; kc < 16; ++kc) {
            // stage gathered x rows
#pragma unroll
            for (int h = 0; h < 2; ++h) {
                int i4 = tid + h * 256;
                int m = i4 >> 4, dd4 = (i4 & 15) * 4;
                size_t t = (size_t)(ent[m] >> 1);
                *(float4*)&xs[m * 64 + dd4] = xld.ld4(t * DDIM + kc * 64 + dd4);
            }
            // stage weight chunk [64 d][64 r], contiguous -> fully coalesced
#pragma unroll
            for (int h = 0; h < 4; ++h) {
                int i4 = tid + h * 256;
                int dl = i4 >> 4, r4 = (i4 & 15) * 4;
                *(float4*)&wt[dl * 64 + r4] = nld.ld4(nbase + (size_t)(kc * 64 + dl) * RDIM + r4);
            }
            __syncthreads();

#pragma unroll 8
            for (int dd = 0; dd < 64; ++dd) {
                float xv0 = xs[(2 * mg) * 64 + dd];
                float xv1 = xs[(2 * mg + 1) * 64 + dd];
                float4 wv = *(const float4*)&wt[dd * 64 + 4 * rg];
                acc0.x += xv0 * wv.x; acc0.y += xv0 * wv.y; acc0.z += xv0 * wv.z; acc0.w += xv0 * wv.w;
                acc1.x += xv1 * wv.x; acc1.y += xv1 * wv.y; acc1.z += xv1 * wv.z; acc1.w += xv1 * wv.w;
            }
            __syncthreads();
        }
        if (2 * mg < valid)
            *(float4*)&wsProj[(size_t)ent[2 * mg] * RDIM + 4 * rg] = acc0;
        if (2 * mg + 1 < valid)
            *(float4*)&wsProj[(size_t)ent[2 * mg + 1] * RDIM + 4 * rg] = acc1;
        __syncthreads();
    }
}

__global__ __launch_bounds__(256) void expert_gemm(const void* x, const void* neurons,
                                                   const int* wsCnt, const int* wsList,
                                                   float* wsProj, const int* flag) {
    __shared__ float xs[32 * 64];
    __shared__ float wt[64 * 64];
    __shared__ int ent[32];
    if (*flag)
        egemm_body(LdF32{(const float*)x}, LdF32{(const float*)neurons}, wsCnt, wsList, wsProj, xs, wt, ent);
    else
        egemm_body(LdBF{(const u16*)x}, LdBF{(const u16*)neurons}, wsCnt, wsList, wsProj, xs, wt, ent);
}

// ---------------- Kernel C: combine w0*p0 + w1*p1 -> f32 ----------------
__global__ __launch_bounds__(256) void combine(const float* __restrict__ wsProj,
                                               const float* __restrict__ wsW,
                                               float* __restrict__ out) {
    const int g = blockIdx.x * 256 + threadIdx.x;  // 0..262143
    const int t = g >> 6, r = g & 63;
    const float w0 = wsW[t * 2], w1 = wsW[t * 2 + 1];
    out[g] = w0 * wsProj[(size_t)t * 128 + r] + w1 * wsProj[(size_t)t * 128 + 64 + r];
}

extern "C" void kernel_launch(void* const* d_in, const int* in_sizes, int n_in,
                              void* d_out, int out_size, void* d_ws, size_t ws_size,
                              hipStream_t stream) {
    const void* x = d_in[0];
    const void* rw = d_in[1];
    const void* neurons = d_in[2];
    float* out = (float*)d_out;

    char* wsc = (char*)d_ws;
    float* wsProj = (float*)wsc;                                   // 8192*64 f32 = 2 MB
    float* wsW = (float*)(wsc + (size_t)T_TOKENS * 2 * RDIM * 4);  // 32 KB
    int* wsCnt = (int*)(wsc + 2 * 1024 * 1024 + 32 * 1024);        // 256 B
    int* wsList = (int*)((char*)wsCnt + 256);                      // 64*1024 int = 256 KB
    int* wsFlag = (int*)((char*)wsList + (size_t)NEXP * LCAP * 4);

    hipMemsetAsync(wsCnt, 0, 256, stream);
    detect_dtype<<<1, 512, 0, stream>>>((const u16*)x, wsFlag);
    score_topk<<<128, 256, 0, stream>>>(x, rw, out, wsW, wsCnt, wsList, wsFlag);
    expert_gemm<<<512, 256, 0, stream>>>(x, neurons, wsCnt, wsList, wsProj, wsFlag);
    combine<<<1024, 256, 0, stream>>>(wsProj, wsW, out);
}

// Round 5
// 188.298 us; speedup vs baseline: 2.2391x; 1.1128x over previous
//
#include <hip/hip_runtime.h>
#include <hip/hip_bf16.h>

// B=2,S=2048 -> T=4096 tokens; D=1024; N=64 experts; R=64; TOP_K=2.
// Inputs runtime-detected f32 vs bf16 (measured: f32). Outputs f32 flat:
// [0,262144) proj; [262144,270336) topk_idx (as float); [270336,278528) topk_w.
// R5: score grid 128->256, expert reads stride-16 (kills 8-way LDS conflicts:
// row stride 68 floats -> 4*ng bank windows, 2-way only); expert_gemm M=16
// tiles + weighted atomicAdd directly into out (wsProj + combine removed).
// d_ws: f32 w[t*2] (32KB); int cnt[64]; int list[64*1024] (256KB); int flag.

typedef unsigned short u16;

__device__ __forceinline__ float bf2f(u16 u) {
    unsigned int v = ((unsigned int)u) << 16;
    float f;
    __builtin_memcpy(&f, &v, 4);
    return f;
}

#define T_TOKENS 4096
#define DDIM 1024
#define NEXP 64
#define RDIM 64
#define LCAP 1024
#define OUT_IDX_OFF 262144
#define OUT_W_OFF 270336

struct LdBF {
    const u16* p;
    __device__ __forceinline__ float4 ld4(size_t i) const {
        ushort4 v = *(const ushort4*)(p + i);
        return make_float4(bf2f(v.x), bf2f(v.y), bf2f(v.z), bf2f(v.w));
    }
};
struct LdF32 {
    const float* p;
    __device__ __forceinline__ float4 ld4(size_t i) const { return *(const float4*)(p + i); }
};

// ------------- dtype detect (0=bf16,1=f32) + zero expert counters ----------
__global__ __launch_bounds__(512) void detect_dtype(const u16* __restrict__ x,
                                                    int* __restrict__ flag,
                                                    int* __restrict__ wsCnt) {
    __shared__ int cnt;
    if (threadIdx.x == 0) cnt = 0;
    if (threadIdx.x < NEXP) wsCnt[threadIdx.x] = 0;
    __syncthreads();
    unsigned e = (x[threadIdx.x] >> 7) & 0xFF;
    atomicAdd(&cnt, (e >= 0x68 && e <= 0x88) ? 1 : 0);
    __syncthreads();
    if (threadIdx.x == 0) *flag = (cnt >= 480) ? 0 : 1;
}

// ---------------- Kernel A: score GEMM + top2 + softmax + expert lists ----
// 256 blocks x 256 threads; 16 tokens/block; K-chunks of 64.
// Thread: token m = tid>>4, experts n = (tid&15) + 16k (k=0..3).
// d-accumulation order identical to round 3/4 (kc*64 + dd ascending, same
// float4 expression) so top-2 decisions reproduce exactly.
template <class LD>
__device__ __forceinline__ void score_body(LD xld, LD rwld,
                                           float* xs /*16*64*/, float* wt /*64*68*/,
                                           float* sc /*16*65*/,
                                           float* out, float* wsW,
                                           int* wsCnt, int* wsList) {
    const int tid = threadIdx.x;
    const size_t t0 = (size_t)blockIdx.x * 16;
    const int m = tid >> 4;    // token 0..15
    const int ng = tid & 15;   // experts ng, ng+16, ng+32, ng+48

    float a[4] = {0.f, 0.f, 0.f, 0.f};

    for (int kc = 0; kc < 16; ++kc) {
        {   // stage x: 16 tokens x 64 d (1 float4/thread)
            int d4 = (tid & 15) * 4;
            *(float4*)&xs[m * 64 + d4] = xld.ld4((t0 + m) * DDIM + kc * 64 + d4);
        }
#pragma unroll
        for (int h = 0; h < 4; ++h) {  // stage rw chunk: 64 n x 64 d, pitch 68
            int i4 = tid + h * 256;
            int n = i4 >> 4, d4 = (i4 & 15) * 4;
            *(float4*)&wt[n * 68 + d4] = rwld.ld4((size_t)n * DDIM + kc * 64 + d4);
        }
        __syncthreads();

#pragma unroll 4
        for (int dd = 0; dd < 64; dd += 4) {
            float4 xa = *(const float4*)&xs[m * 64 + dd];   // broadcast in 16-lane group
#pragma unroll
            for (int k = 0; k < 4; ++k) {                    // stride-16 rows: 2-way only
                float4 wv = *(const float4*)&wt[(ng + 16 * k) * 68 + dd];
                a[k] += xa.x * wv.x + xa.y * wv.y + xa.z * wv.z + xa.w * wv.w;
            }
        }
        __syncthreads();
    }

#pragma unroll
    for (int k = 0; k < 4; ++k) sc[m * 65 + ng + 16 * k] = a[k];
    __syncthreads();

    if (tid < 16) {
        const float* s = &sc[tid * 65];
        float best = -1e30f, secv = -1e30f;
        int bi = 0, si = 0;
        for (int j = 0; j < NEXP; ++j) {
            float v = s[j];
            if (v > best) { secv = best; si = bi; best = v; bi = j; }
            else if (v > secv) { secv = v; si = j; }
        }
        float w0 = 1.0f / (1.0f + expf(secv - best));
        float w1 = 1.0f - w0;
        size_t t = t0 + tid;
        out[OUT_IDX_OFF + t * 2 + 0] = (float)bi;
        out[OUT_IDX_OFF + t * 2 + 1] = (float)si;
        out[OUT_W_OFF + t * 2 + 0] = w0;
        out[OUT_W_OFF + t * 2 + 1] = w1;
        wsW[t * 2 + 0] = w0;
        wsW[t * 2 + 1] = w1;
        int p0 = atomicAdd(&wsCnt[bi], 1);
        if (p0 < LCAP) wsList[bi * LCAP + p0] = (int)(t * 2 + 0);
        int p1 = atomicAdd(&wsCnt[si], 1);
        if (p1 < LCAP) wsList[si * LCAP + p1] = (int)(t * 2 + 1);
    }
}

__global__ __launch_bounds__(256) void score_topk(const void* x, const void* rw,
                                                  float* out, float* wsW,
                                                  int* wsCnt, int* wsList,
                                                  const int* flag) {
    __shared__ float xs[16 * 64];
    __shared__ float wt[64 * 68];
    __shared__ float sc[16 * 65];
    if (*flag)
        score_body(LdF32{(const float*)x}, LdF32{(const float*)rw}, xs, wt, sc, out, wsW, wsCnt, wsList);
    else
        score_body(LdBF{(const u16*)x}, LdBF{(const u16*)rw}, xs, wt, sc, out, wsW, wsCnt, wsList);
}

// ---------------- Kernel B: per-expert tiled GEMM -> weighted atomic out ---
// 512 blocks: expert n = bid & 63, j = bid >> 6 (M-tiles of 16, stride 128).
template <class LD>
__device__ __forceinline__ void egemm_body(LD xld, LD nld,
                                           const int* wsCnt, const int* wsList,
                                           const float* wsW, float* out,
                                           float* xs /*16*64*/, float* wt /*64*64*/,
                                           int* ent /*16*/) {
    const int tid = threadIdx.x;
    const int n = blockIdx.x & 63;
    const int j = blockIdx.x >> 6;
    const int cnt = min(wsCnt[n], LCAP);
    const int m = tid >> 4;    // row 0..15
    const int rg = tid & 15;   // r = 4rg..4rg+3
    const size_t nbase = (size_t)n * DDIM * RDIM;

    for (int base = j * 16; base < cnt; base += 128) {
        const int valid = min(16, cnt - base);
        if (tid < 16)
            ent[tid] = wsList[n * LCAP + base + ((tid < valid) ? tid : 0)];
        __syncthreads();

        float4 acc = make_float4(0.f, 0.f, 0.f, 0.f);
        for (int kc = 0; kc < 16; ++kc) {
            {   // gather x rows (1 float4/thread)
                int d4 = (tid & 15) * 4;
                size_t t = (size_t)(ent[m] >> 1);
                *(float4*)&xs[m * 64 + d4] = xld.ld4(t * DDIM + kc * 64 + d4);
            }
#pragma unroll
            for (int h = 0; h < 4; ++h) {  // weight chunk [64 d][64 r]
                int i4 = tid + h * 256;
                int dl = i4 >> 4, r4 = (i4 & 15) * 4;
                *(float4*)&wt[dl * 64 + r4] = nld.ld4(nbase + (size_t)(kc * 64 + dl) * RDIM + r4);
            }
            __syncthreads();

#pragma unroll 8
            for (int dd = 0; dd < 64; ++dd) {
                float xv = xs[m * 64 + dd];                       // broadcast
                float4 wv = *(const float4*)&wt[dd * 64 + 4 * rg]; // consecutive: 2-way
                acc.x += xv * wv.x; acc.y += xv * wv.y;
                acc.z += xv * wv.z; acc.w += xv * wv.w;
            }
            __syncthreads();
        }

        if (m < valid) {
            int t2 = ent[m];
            float w = wsW[t2];
            float* op = out + (size_t)(t2 >> 1) * RDIM + 4 * rg;
            atomicAdd(op + 0, w * acc.x);
            atomicAdd(op + 1, w * acc.y);
            atomicAdd(op + 2, w * acc.z);
            atomicAdd(op + 3, w * acc.w);
        }
        __syncthreads();  // protect ent before next tile's overwrite
    }
}

__global__ __launch_bounds__(256) void expert_gemm(const void* x, const void* neurons,
                                                   const int* wsCnt, const int* wsList,
                                                   const float* wsW, float* out,
                                                   const int* flag) {
    __shared__ float xs[16 * 64];
    __shared__ float wt[64 * 64];
    __shared__ int ent[16];
    if (*flag)
        egemm_body(LdF32{(const float*)x}, LdF32{(const float*)neurons}, wsCnt, wsList, wsW, out, xs, wt, ent);
    else
        egemm_body(LdBF{(const u16*)x}, LdBF{(const u16*)neurons}, wsCnt, wsList, wsW, out, xs, wt, ent);
}

extern "C" void kernel_launch(void* const* d_in, const int* in_sizes, int n_in,
                              void* d_out, int out_size, void* d_ws, size_t ws_size,
                              hipStream_t stream) {
    const void* x = d_in[0];
    const void* rw = d_in[1];
    const void* neurons = d_in[2];
    float* out = (float*)d_out;

    char* wsc = (char*)d_ws;
    float* wsW = (float*)wsc;                                  // 32 KB
    int* wsCnt = (int*)(wsc + 32 * 1024);                      // 256 B
    int* wsList = (int*)((char*)wsCnt + 256);                  // 256 KB
    int* wsFlag = (int*)((char*)wsList + (size_t)NEXP * LCAP * 4);

    hipMemsetAsync(out, 0, (size_t)T_TOKENS * RDIM * 4, stream);  // proj region only
    detect_dtype<<<1, 512, 0, stream>>>((const u16*)x, wsFlag, wsCnt);
    score_topk<<<256, 256, 0, stream>>>(x, rw, out, wsW, wsCnt, wsList, wsFlag);
    expert_gemm<<<512, 256, 0, stream>>>(x, neurons, wsCnt, wsList, wsW, out, wsFlag);
}